// Round 4
// baseline (175.557 us; speedup 1.0000x reference)
//
#include <hip/hip_runtime.h>

#define BATCH   64
#define CHANS   36
#define ANCH    8400
#define NCLS    32
#define MAXDET  100
#define CONF    0.25f
#define KTOP    512             // matrix region (bucket-aligned cutoff K <= KTOP)
#define NBUCK   2048
#define BUCK0   (0x3E800000u >> 13)   // bucket base: 8192-ulp buckets over [0.25,1.0)
#define STPB    512             // sort kernel threads
#define SNW     (STPB / 64)
#define SNLD    17              // ceil(8400/512)

typedef unsigned long long u64;
typedef unsigned int       u32;

// exact ref IoU-threshold compare: for uni>0, RN(inter/uni) > 0.45f <=> inter > M*uni
// (a = suppressor box, matching reference op order; f32 ops, no contraction)
__device__ __forceinline__ bool iou_gt(float ay1, float ax1, float ay2, float ax2, float aar,
                                       float by1, float bx1, float by2, float bx2, float bar,
                                       double M) {
#pragma clang fp contract(off)
    float iy1 = fmaxf(ay1, by1), ix1 = fmaxf(ax1, bx1);
    float iy2 = fminf(ay2, by2), ix2 = fminf(ax2, bx2);
    float inter = fmaxf(iy2 - iy1, 0.f) * fmaxf(ix2 - ix1, 0.f);
    float uni = (aar + bar) - inter;
    return (double)inter > M * (double)uni;
}

// ---------------- Phase A: per-anchor prep, float2, 2 anchors/thread ----------------
// 17x64 = 1088 blocks -> ~17 waves/CU of TLP for the 36-deep load chain.
__global__ __launch_bounds__(256) void yolo_prep(const float* __restrict__ in,
                                                 float4* __restrict__ wbox,
                                                 u64* __restrict__ wk64) {
#pragma clang fp contract(off)
    const int G2 = ANCH / 2;            // 4200
    int g = blockIdx.x * 256 + threadIdx.x;
    if (g >= G2) return;
    int b = blockIdx.y;
    const float2* p = (const float2*)(in + (size_t)b * (CHANS * ANCH));
    float2 xc = p[0 * G2 + g], yc = p[1 * G2 + g], ww = p[2 * G2 + g], hh = p[3 * G2 + g];
    float2 best = p[4 * G2 + g];
    uint2 bc = make_uint2(0, 0);
#pragma unroll
    for (int k = 1; k < NCLS; ++k) {
        float2 v = p[(4 + k) * G2 + g];
        if (v.x > best.x) { best.x = v.x; bc.x = k; }   // strict >: first index (np.argmax)
        if (v.y > best.y) { best.y = v.y; bc.y = k; }
    }
    int a0 = b * ANCH + 2 * g;
    u64* wk = wk64 + (size_t)b * ANCH + 2 * g;
#define PREP_C(C, I)                                                      \
    {                                                                     \
        float Y1 = fminf(fmaxf(yc.C - hh.C * 0.5f, 0.f), 1.f);            \
        float X1 = fminf(fmaxf(xc.C - ww.C * 0.5f, 0.f), 1.f);            \
        float Y2 = fminf(fmaxf(yc.C + hh.C * 0.5f, 0.f), 1.f);            \
        float X2 = fminf(fmaxf(xc.C + ww.C * 0.5f, 0.f), 1.f);            \
        wbox[a0 + I] = make_float4(Y1, X1, Y2, X2);                       \
        int a_ = 2 * g + I;                                               \
        wk[I] = (best.C >= CONF)                                          \
            ? (((u64)__float_as_uint(best.C) << 32) |                     \
               ((u64)(16383 - a_) << 18) | (u64)(bc.C & 31u))             \
            : 0ull;                                                       \
    }
    PREP_C(x, 0) PREP_C(y, 1)
#undef PREP_C
}

// ---------------- Phase B1: bucket sort (in place, global) ----------------
// Produces: gk = keys in score-descending bucket order (slots [0,T)),
// meta = {K, T} with K = largest bucket-aligned boundary <= KTOP.
// Bucket-aligned K guarantees: every key in [0,K) > every key in [K,T),
// so the top-K suppression matrix is closed (exactness of phase B2/B3).
__global__ __launch_bounds__(STPB) void yolo_sort(u64* __restrict__ wk64,
                                                  u32* __restrict__ meta) {
    int b = blockIdx.x, t = threadIdx.x;
    u64* gk = wk64 + (size_t)b * ANCH;

    __shared__ u32 hist[NBUCK];
    __shared__ u32 wvcnt[SNW];
    __shared__ u32 kred[SNW];

    for (int i = t; i < NBUCK; i += STPB) hist[i] = 0u;
    __syncthreads();

    u64 kk[SNLD];
#pragma unroll
    for (int j = 0; j < SNLD; ++j) {
        int a = t + j * STPB;
        u64 k = (a < ANCH) ? gk[a] : 0ull;
        kk[j] = k;
        if (k != 0ull) atomicAdd(&hist[(int)((u32)(k >> 45) - BUCK0)], 1u);
    }
    __syncthreads();

    // prefix scan over 2048 counts in rank order (rank r = 2047 - bucket)
    int u0 = t * 4;
    u32 c0 = hist[2047 - u0], c1 = hist[2047 - (u0 + 1)],
        c2 = hist[2047 - (u0 + 2)], c3 = hist[2047 - (u0 + 3)];
    u32 l1 = c0 + c1, l2 = l1 + c2, Su = l2 + c3;
    u32 x = Su;
#pragma unroll
    for (int d = 1; d < 64; d <<= 1) {
        u32 y = __shfl_up(x, d, 64);
        if ((t & 63) >= d) x += y;
    }
    if ((t & 63) == 63) wvcnt[t >> 6] = x;
    __syncthreads();
    int wb = 0;
    for (int w = 0; w < (t >> 6); ++w) wb += (int)wvcnt[w];
    int T = 0;
    for (int w = 0; w < SNW; ++w) T += (int)wvcnt[w];
    u32 excl = (u32)wb + x - Su;         // exclusive start of my 4-rank group
    hist[u0]     = excl;                 // scatter cursors, by rank
    hist[u0 + 1] = excl + c0;
    hist[u0 + 2] = excl + l1;
    hist[u0 + 3] = excl + l2;
    __syncthreads();

    // in-place scatter (all loads of gk completed before the barriers above)
#pragma unroll
    for (int j = 0; j < SNLD; ++j) {
        if (kk[j] != 0ull) {
            int r = 2047 - (int)((u32)(kk[j] >> 45) - BUCK0);
            u32 pos = atomicAdd(&hist[r], 1u);
            gk[pos] = kk[j];
        }
    }
    __syncthreads();

    // K = max boundary <= KTOP (post-scatter cursor = inclusive end boundary)
    u32 kb = 0;
#pragma unroll
    for (int q = 0; q < 4; ++q) {
        u32 v = hist[u0 + q];
        if (v <= (u32)KTOP && v > kb) kb = v;
    }
#pragma unroll
    for (int sh = 1; sh < 64; sh <<= 1) {
        u32 o = __shfl_xor(kb, sh, 64);
        if (o > kb) kb = o;
    }
    if ((t & 63) == 0) kred[t >> 6] = kb;
    __syncthreads();
    if (t == 0) {
        u32 K = 0;
        for (int w = 0; w < SNW; ++w) if (kred[w] > K) K = kred[w];
        meta[b * 4 + 0] = K;
        meta[b * 4 + 1] = (u32)T;
    }
}

// ---------------- Phase B2: suppression-bit matrix over top-K (wide) ----------------
// grid (BATCH, 8) x 256: block (b,y) computes rows [y*64, y*64+64).
// Supp[row j][bit i] = (key_i > key_j) && IoU(i,j) > thr.
__global__ __launch_bounds__(256) void yolo_matrix(const float4* __restrict__ wbox,
                                                   const u64* __restrict__ wk64,
                                                   const u32* __restrict__ meta,
                                                   u64* __restrict__ gS) {
#pragma clang fp contract(off)
    const double M = (double)0.45f + 0x1p-26;
    int b = blockIdx.x, t = threadIdx.x;
    const float4* bx = wbox + (size_t)b * ANCH;
    const u64* gk = wk64 + (size_t)b * ANCH;
    int K = (int)meta[b * 4 + 0];

    __shared__ u64    ck[KTOP];
    __shared__ float4 cb[KTOP];
    __shared__ float  ca[KTOP];

    for (int i = t; i < KTOP; i += 256) {
        u64 k = (i < K) ? gk[i] : 0ull;
        ck[i] = k;
        float4 bb = make_float4(0.f, 0.f, 0.f, 0.f);
        if (k != 0ull) {
            int a = 16383 - (int)((k >> 18) & 0x3FFFull);
            bb = bx[a];
        }
        cb[i] = bb;
        ca[i] = (bb.z - bb.x) * (bb.w - bb.y);
    }
    __syncthreads();

    int row = blockIdx.y * 64 + (t >> 2);
    int seg = t & 3;
    u64 kr = ck[row];
    float4 rb = cb[row];
    float rar = ca[row];
    u64 w0 = 0ull, w1 = 0ull;
    int base0 = seg * 128;
#pragma unroll 4
    for (int j = 0; j < 64; ++j) {
        {
            int i = base0 + j;
            u64 ki = ck[i];
            if ((ki > kr) && iou_gt(cb[i].x, cb[i].y, cb[i].z, cb[i].w, ca[i],
                                    rb.x, rb.y, rb.z, rb.w, rar, M))
                w0 |= 1ull << j;
        }
        {
            int i = base0 + 64 + j;
            u64 ki = ck[i];
            if ((ki > kr) && iou_gt(cb[i].x, cb[i].y, cb[i].z, cb[i].w, ca[i],
                                    rb.x, rb.y, rb.z, rb.w, rar, M))
                w1 |= 1ull << j;
        }
    }
    ulonglong2 wv; wv.x = w0; wv.y = w1;
    *(ulonglong2*)&gS[(size_t)b * (KTOP * 8) + (size_t)row * 8 + seg * 2] = wv;
}

// ---------------- Phase B3: ballot fixpoint + emission (+ exact rare-path) ----------------
__global__ __launch_bounds__(256) void yolo_resolve(const float4* __restrict__ wbox,
                                                    u64* __restrict__ wk64,
                                                    const u64* __restrict__ gS,
                                                    const u32* __restrict__ meta,
                                                    float* __restrict__ out) {
#pragma clang fp contract(off)
    const double M = (double)0.45f + 0x1p-26;
    int b = blockIdx.x, t = threadIdx.x;
    const float4* bx = wbox + (size_t)b * ANCH;
    u64* gk = wk64 + (size_t)b * ANCH;
    int K = (int)meta[b * 4 + 0], T = (int)meta[b * 4 + 1];

    __shared__ u64   ck[KTOP];           // 4 KB
    __shared__ u64   SP[KTOP * 9];       // 36.9 KB, 9-stride pad (bank-conflict-free rows)
    __shared__ u64   selKey[KTOP];       // 4 KB
    __shared__ float selb[MAXDET][5];    // selected boxes+areas (rare-path prekill)
    __shared__ u64   redm[4];
    __shared__ int   selTotS;

    float* outBox = out + (size_t)b * (MAXDET * 4);
    float* outCls = out + (size_t)(BATCH * MAXDET * 4) + b * MAXDET;
    float* outScr = out + (size_t)(BATCH * MAXDET * 5) + b * MAXDET;
    float* outNum = out + (size_t)(BATCH * MAXDET * 6) + b;

    for (int i = t; i < KTOP; i += 256) ck[i] = (i < K) ? gk[i] : 0ull;
    const u64* gSb = gS + (size_t)b * (KTOP * 8);
    for (int i = t; i < KTOP * 8; i += 256) SP[(i >> 3) * 9 + (i & 7)] = gSb[i];
    __syncthreads();

    // ---- ballot fixpoint over top-K (wave 0; exact greedy) ----
    u64 S[8];
#pragma unroll
    for (int w = 0; w < 8; ++w) S[w] = 0ull;
    if (t < 64) {
        int L = t;
        u64 U[8];
#pragma unroll
        for (int w = 0; w < 8; ++w) U[w] = __ballot(ck[(w << 6) + L] != 0ull);
        for (int it = 0; it < KTOP; ++it) {
            if (!(U[0] | U[1] | U[2] | U[3] | U[4] | U[5] | U[6] | U[7])) break;
            u64 D[8];
#pragma unroll
            for (int w = 0; w < 8; ++w) {
                const u64* rm = &SP[((w << 6) + L) * 9];
                u64 pend = (rm[0] & U[0]) | (rm[1] & U[1]) | (rm[2] & U[2]) | (rm[3] & U[3])
                         | (rm[4] & U[4]) | (rm[5] & U[5]) | (rm[6] & U[6]) | (rm[7] & U[7]);
                D[w] = __ballot(((U[w] >> L) & 1ull) && (pend == 0ull));
            }
#pragma unroll
            for (int w = 0; w < 8; ++w) { S[w] |= D[w]; U[w] &= ~D[w]; }
#pragma unroll
            for (int w = 0; w < 8; ++w) {
                const u64* rm = &SP[((w << 6) + L) * 9];
                u64 hit = (rm[0] & D[0]) | (rm[1] & D[1]) | (rm[2] & D[2]) | (rm[3] & D[3])
                        | (rm[4] & D[4]) | (rm[5] & D[5]) | (rm[6] & D[6]) | (rm[7] & D[7]);
                U[w] &= ~__ballot(((U[w] >> L) & 1ull) && (hit != 0ull));
            }
        }
        if (t == 0) {
            int c = 0;
#pragma unroll
            for (int w = 0; w < 8; ++w) c += (int)__popcll(S[w]);
            selTotS = c;
        }
    }
    __syncthreads();

    // ---- build dense selected-key list (slot order) ----
    if (t < 64) {
        int L = t, base = 0;
#pragma unroll
        for (int w = 0; w < 8; ++w) {
            u64 Sw = S[w];
            if ((Sw >> L) & 1ull) {
                int r = base + (int)__popcll(Sw & ((1ull << L) - 1ull));
                selKey[r] = ck[(w << 6) + L];
            }
            base += (int)__popcll(Sw);
        }
    }
    __syncthreads();

    int sTot = selTotS;
    int s = sTot < MAXDET ? sTot : MAXDET;

    // ---- emission in exact key order (parallel rank-by-count) ----
    if (t < 64) {
        int L = t;
#pragma unroll
        for (int w = 0; w < 8; ++w) {
            if ((S[w] >> L) & 1ull) {
                u64 myk = ck[(w << 6) + L];
                int pos = 0;
                for (int j = 0; j < sTot; ++j) pos += (selKey[j] > myk) ? 1 : 0;
                if (pos < MAXDET) {
                    int a = 16383 - (int)((myk >> 18) & 0x3FFFull);
                    float4 bb = bx[a];
                    outScr[pos] = __uint_as_float((u32)(myk >> 32));
                    outCls[pos] = (float)((u32)myk & 31u);
                    outBox[pos * 4 + 0] = bb.x; outBox[pos * 4 + 1] = bb.y;
                    outBox[pos * 4 + 2] = bb.z; outBox[pos * 4 + 3] = bb.w;
                    selb[pos][0] = bb.x; selb[pos][1] = bb.y; selb[pos][2] = bb.z;
                    selb[pos][3] = bb.w; selb[pos][4] = (bb.z - bb.x) * (bb.w - bb.y);
                }
            }
        }
    }
    __syncthreads();

    // ---- exact continuation over gk[K..T) (rare; never triggers on this data) ----
    if (s < MAXDET && T > K) {
        int NR = T - K;
        u64* rk = gk + K;
        for (int i = t; i < NR; i += 256) {       // prekill vs prior selections
            u64 k = rk[i];
            if (!k) continue;
            int a = 16383 - (int)((k >> 18) & 0x3FFFull);
            float4 bb = bx[a];
            float ar = (bb.z - bb.x) * (bb.w - bb.y);
            for (int j = 0; j < s; ++j) {
                if (iou_gt(selb[j][0], selb[j][1], selb[j][2], selb[j][3], selb[j][4],
                           bb.x, bb.y, bb.z, bb.w, ar, M)) { rk[i] = 0ull; break; }
            }
        }
        __syncthreads();
        while (s < MAXDET) {
            u64 best = 0ull;
            for (int i = t; i < NR; i += 256) { u64 k = rk[i]; if (k > best) best = k; }
#pragma unroll
            for (int sh = 1; sh < 64; sh <<= 1) {
                u64 o = __shfl_xor(best, sh, 64);
                if (o > best) best = o;
            }
            if ((t & 63) == 0) redm[t >> 6] = best;
            __syncthreads();
            best = redm[0];
            for (int w = 1; w < 4; ++w) if (redm[w] > best) best = redm[w];
            if (best == 0ull) break;
            int a = 16383 - (int)((best >> 18) & 0x3FFFull);
            float4 nb = bx[a];
            float nar = (nb.z - nb.x) * (nb.w - nb.y);
            if (t == 0) {
                outScr[s] = __uint_as_float((u32)(best >> 32));
                outCls[s] = (float)((u32)best & 31u);
                outBox[s * 4 + 0] = nb.x; outBox[s * 4 + 1] = nb.y;
                outBox[s * 4 + 2] = nb.z; outBox[s * 4 + 3] = nb.w;
            }
            for (int i = t; i < NR; i += 256) {
                u64 k = rk[i];
                if (k != 0ull) {
                    if (k == best) rk[i] = 0ull;
                    else {
                        int a2 = 16383 - (int)((k >> 18) & 0x3FFFull);
                        float4 bb = bx[a2];
                        float ar = (bb.z - bb.x) * (bb.w - bb.y);
                        if (iou_gt(nb.x, nb.y, nb.z, nb.w, nar,
                                   bb.x, bb.y, bb.z, bb.w, ar, M)) rk[i] = 0ull;
                    }
                }
            }
            ++s;
            __syncthreads();
        }
    }

    for (int q = s + t; q < MAXDET; q += 256) {
        outScr[q] = 0.f; outCls[q] = 0.f;
        outBox[q * 4 + 0] = 0.f; outBox[q * 4 + 1] = 0.f;
        outBox[q * 4 + 2] = 0.f; outBox[q * 4 + 3] = 0.f;
    }
    if (t == 0) *outNum = (float)s;
}

extern "C" void kernel_launch(void* const* d_in, const int* in_sizes, int n_in,
                              void* d_out, int out_size, void* d_ws, size_t ws_size,
                              hipStream_t stream) {
    const float* in = (const float*)d_in[0];
    float* out = (float*)d_out;
    // workspace: boxes float4 8.6MB | keys u64 4.3MB | Supp bits 2MB | meta 1KB
    float4* wbox = (float4*)d_ws;
    u64*    wk64 = (u64*)((char*)d_ws + (size_t)BATCH * ANCH * 16);
    u64*    gS   = (u64*)((char*)d_ws + (size_t)BATCH * ANCH * 24);
    u32*    meta = (u32*)((char*)d_ws + (size_t)BATCH * ANCH * 24 + (size_t)BATCH * KTOP * 64);

    dim3 gp((ANCH / 2 + 255) / 256, BATCH);
    yolo_prep<<<gp, 256, 0, stream>>>(in, wbox, wk64);
    yolo_sort<<<BATCH, STPB, 0, stream>>>(wk64, meta);
    yolo_matrix<<<dim3(BATCH, 8), 256, 0, stream>>>(wbox, wk64, meta, gS);
    yolo_resolve<<<BATCH, 256, 0, stream>>>(wbox, wk64, gS, meta, out);
}